// Round 1
// 4528.027 us; speedup vs baseline: 2.2132x; 2.2132x over previous
//
#include <hip/hip_runtime.h>
#include <math.h>

typedef __attribute__((ext_vector_type(8))) short short8v;
typedef __attribute__((ext_vector_type(4))) short short4v;
typedef __attribute__((ext_vector_type(4))) float f32x4;

static constexpr int EMB    = 1024;
static constexpr int SEQ    = 1024;
static constexpr int NBATCH = 4;
static constexpr int NHEAD  = 16;
static constexpr int NLAY   = 6;
static constexpr int NVOCAB = 50257;
static constexpr int NROWS  = 4096;   // NBATCH*SEQ
static constexpr int QKVD   = 3072;
static constexpr int FFDIM  = 4096;
static constexpr int NVOC_PAD = 50304;  // 393*128

__device__ __forceinline__ short f2bf(float f) {
  union { float f; unsigned u; } v; v.f = f;
  unsigned u = (v.u + 0x7fffu + ((v.u >> 16) & 1u)) >> 16;
  return (short)u;
}

__device__ __forceinline__ short8v pack8(const float4& a, const float4& b) {
  short8v r;
  r[0] = f2bf(a.x); r[1] = f2bf(a.y); r[2] = f2bf(a.z); r[3] = f2bf(a.w);
  r[4] = f2bf(b.x); r[5] = f2bf(b.y); r[6] = f2bf(b.z); r[7] = f2bf(b.w);
  return r;
}

// async global->LDS, 16B per lane; LDS dest is wave-uniform base + lane*16
__device__ __forceinline__ void gload16(const short* g, short* l) {
  __builtin_amdgcn_global_load_lds(
      (const __attribute__((address_space(1))) void*)g,
      (__attribute__((address_space(3))) void*)l, 16, 0, 0);
}

// ---------------- weight f32 -> bf16 (zero-pads [nsrc, ntot)) ----------------
__global__ __launch_bounds__(256) void convbf_kernel(const float* __restrict__ src,
    short* __restrict__ dst, long long ntot, long long nsrc) {
  long long i = ((long long)blockIdx.x * 256 + threadIdx.x) * 8;
  const long long stride = (long long)gridDim.x * 256 * 8;
  for (; i < ntot; i += stride) {
    short8v o = {0, 0, 0, 0, 0, 0, 0, 0};
    if (i < nsrc) {
      float4 a = *(const float4*)(src + i);
      float4 b = *(const float4*)(src + i + 4);
      o = pack8(a, b);
    }
    *(short8v*)(dst + i) = o;
  }
}

// ---------------- embedding: x = wte[idx] + wpe[t] ----------------
__global__ __launch_bounds__(256) void embed_kernel(const int* __restrict__ idx,
    const float* __restrict__ wte, const float* __restrict__ wpe,
    float* __restrict__ x) {
  const int row = blockIdx.x, tid = threadIdx.x;
  const int tok = idx[row];
  const int t = row & (SEQ - 1);
  float4 a = ((const float4*)(wte + (size_t)tok * EMB))[tid];
  float4 p = ((const float4*)(wpe + (size_t)t * EMB))[tid];
  float4 o; o.x = a.x + p.x; o.y = a.y + p.y; o.z = a.z + p.z; o.w = a.w + p.w;
  ((float4*)(x + (size_t)row * EMB))[tid] = o;
}

// ---------------- layernorm: f32 in, bf16 out, one block per row ------------
__global__ __launch_bounds__(256) void ln_kernel(const float* __restrict__ x,
    const float* __restrict__ w, const float* __restrict__ b,
    short* __restrict__ out) {
  const int row = blockIdx.x, tid = threadIdx.x;
  const int wave = tid >> 6, lane = tid & 63;
  const float4 v = ((const float4*)(x + (size_t)row * EMB))[tid];
  float s  = v.x + v.y + v.z + v.w;
  float s2 = v.x * v.x + v.y * v.y + v.z * v.z + v.w * v.w;
  for (int m = 1; m < 64; m <<= 1) { s += __shfl_xor(s, m, 64); s2 += __shfl_xor(s2, m, 64); }
  __shared__ float ps[4], ps2[4];
  if (lane == 0) { ps[wave] = s; ps2[wave] = s2; }
  __syncthreads();
  s  = ps[0] + ps[1] + ps[2] + ps[3];
  s2 = ps2[0] + ps2[1] + ps2[2] + ps2[3];
  const float mu = s * (1.0f / EMB);
  const float var = s2 * (1.0f / EMB) - mu * mu;
  const float rs = rsqrtf(var + 1e-5f);
  const float4 wv = ((const float4*)w)[tid];
  const float4 bv = ((const float4*)b)[tid];
  short4v o;
  o[0] = f2bf((v.x - mu) * rs * wv.x + bv.x);
  o[1] = f2bf((v.y - mu) * rs * wv.y + bv.y);
  o[2] = f2bf((v.z - mu) * rs * wv.z + bv.z);
  o[3] = f2bf((v.w - mu) * rs * wv.w + bv.w);
  *(short4v*)(out + (size_t)row * EMB + tid * 4) = o;
}

// ---------------- GEMM: C = A @ Bt^T, A: MxK bf16, Bt: NbxK bf16 ------------
// m97-structure: 128x128 tile, BK=64, global_load_lds w16 (linear LDS dest,
// inverse-XOR-swizzled global source), XOR-swizzled ds_read_b128 (2-way = free).
// ep: 0 = f32 store w/ col<N guard (lm), 1 = f32 store + residual,
//     2 = bf16 store, 3 = bf16 store + exact GELU
__global__ __launch_bounds__(256) void gemm_bt(const short* __restrict__ A,
    const short* __restrict__ Bt, float* __restrict__ C,
    const float* __restrict__ R, int M, int N, int K, int ep) {
  __shared__ short lds_a[128 * 64];
  __shared__ short lds_b[128 * 64];
  const int tid = threadIdx.x;
  const int wave = tid >> 6, lane = tid & 63, quad = lane >> 4, l16 = lane & 15;
  const int wrow = (wave >> 1) * 64, wcol = (wave & 1) * 64;
  const int m0 = blockIdx.y * 128, n0 = blockIdx.x * 128;
  // staging: thread covers row srow (within 32-row slab), 16B chunk gchk of 8.
  // source chunk is XOR-permuted so linear LDS holds chunk c = global c^(row&7).
  const int srow = tid >> 3;                    // 0..31
  const int gchk = (tid & 7) ^ (srow & 7);      // involution, constant over p
  const short* Ab = A + (size_t)(m0 + srow) * K + gchk * 8;
  const short* Bb = Bt + (size_t)(n0 + srow) * K + gchk * 8;
  short* la = lds_a + wave * 512;               // wave*8 rows * 64
  short* lb = lds_b + wave * 512;
  const int rx = l16 & 7;                       // row&7 for fragment reads
  f32x4 acc[4][4] = {};
  for (int k0 = 0; k0 < K; k0 += 64) {
    __syncthreads();
    for (int p = 0; p < 4; ++p) {
      gload16(Ab + (size_t)p * 32 * K + k0, la + p * 2048);
      gload16(Bb + (size_t)p * 32 * K + k0, lb + p * 2048);
    }
    __syncthreads();   // compiler drains vmcnt(0) before barrier
    for (int ks = 0; ks < 2; ++ks) {
      const int kc = (((ks << 2) | quad) ^ rx) << 3;  // swizzled k-chunk offset
      short8v af[4], bf[4];
      for (int i = 0; i < 4; ++i) {
        af[i] = *(const short8v*)&lds_a[(wrow + i * 16 + l16) * 64 + kc];
        bf[i] = *(const short8v*)&lds_b[(wcol + i * 16 + l16) * 64 + kc];
      }
      for (int i = 0; i < 4; ++i)
        for (int j = 0; j < 4; ++j)
          acc[i][j] = __builtin_amdgcn_mfma_f32_16x16x32_bf16(af[i], bf[j], acc[i][j], 0, 0, 0);
    }
  }
  if (ep == 0) {
    for (int i = 0; i < 4; ++i)
      for (int j = 0; j < 4; ++j) {
        int col = n0 + wcol + j * 16 + l16;
        if (col >= N) continue;
        for (int r = 0; r < 4; ++r) {
          int row = m0 + wrow + i * 16 + quad * 4 + r;
          C[(size_t)row * N + col] = acc[i][j][r];
        }
      }
  } else if (ep == 1) {
    for (int i = 0; i < 4; ++i)
      for (int j = 0; j < 4; ++j) {
        int col = n0 + wcol + j * 16 + l16;
        for (int r = 0; r < 4; ++r) {
          int row = m0 + wrow + i * 16 + quad * 4 + r;
          C[(size_t)row * N + col] = acc[i][j][r] + R[(size_t)row * N + col];
        }
      }
  } else {
    short* Cs = (short*)C;
    for (int i = 0; i < 4; ++i)
      for (int j = 0; j < 4; ++j) {
        int col = n0 + wcol + j * 16 + l16;
        for (int r = 0; r < 4; ++r) {
          int row = m0 + wrow + i * 16 + quad * 4 + r;
          float v = acc[i][j][r];
          if (ep == 3) v = 0.5f * v * (1.0f + erff(v * 0.70710678118f));
          Cs[(size_t)row * N + col] = f2bf(v);
        }
      }
  }
}

// ---------------- flash attention: bf16 qkv in, bf16 y out ------------------
__global__ __launch_bounds__(256) void attn_kernel(const short* __restrict__ qkv,
                                                   short* __restrict__ y) {
  const int qt = blockIdx.x, h = blockIdx.y, bb = blockIdx.z;
  const int tid = threadIdx.x;
  const int wave = tid >> 6, lane = tid & 63, quad = lane >> 4, l16 = lane & 15;
  __shared__ short vt[64 * 72];        // V^T tile: [dim][key]
  __shared__ short pl[4 * 16 * 72];    // P per wave: [m][key]
  const short* base = qkv + (size_t)bb * SEQ * QKVD;
  short8v qf[2];
  {
    const short* qp = base + (size_t)(qt * 64 + wave * 16 + l16) * QKVD + h * 64;
    for (int ks = 0; ks < 2; ++ks)
      qf[ks] = *(const short8v*)(qp + ks * 32 + quad * 8);
  }
  f32x4 o[4] = {};
  float mrun[4] = {-INFINITY, -INFINITY, -INFINITY, -INFINITY};
  float lrun[4] = {0.f, 0.f, 0.f, 0.f};
  const float scale = 0.125f;  // 1/sqrt(64)
  for (int kt = 0; kt <= qt; ++kt) {
    __syncthreads();
    {   // stage V^T tile
      int key = tid >> 4;
      int d4 = (tid & 15) * 4;
      for (int p = 0; p < 4; ++p) {
        int kk = p * 16 + key;
        const short* vp = base + (size_t)(kt * 64 + kk) * QKVD + 2 * EMB + h * 64 + d4;
        short4v v = *(const short4v*)vp;
        vt[(d4 + 0) * 72 + kk] = v[0];
        vt[(d4 + 1) * 72 + kk] = v[1];
        vt[(d4 + 2) * 72 + kk] = v[2];
        vt[(d4 + 3) * 72 + kk] = v[3];
      }
    }
    __syncthreads();
    // S = Q K^T (K read straight from global as B-fragments)
    f32x4 s[4] = {};
    for (int nt = 0; nt < 4; ++nt) {
      const short* kp = base + (size_t)(kt * 64 + nt * 16 + l16) * QKVD + EMB + h * 64;
      for (int ks = 0; ks < 2; ++ks) {
        short8v kf = *(const short8v*)(kp + ks * 32 + quad * 8);
        s[nt] = __builtin_amdgcn_mfma_f32_16x16x32_bf16(qf[ks], kf, s[nt], 0, 0, 0);
      }
    }
    // online softmax
    const bool diag = (kt == qt);
    float alpha[4];
    float p[4][4];
    for (int r = 0; r < 4; ++r) {
      const int qrow_l = wave * 16 + quad * 4 + r;
      float mt = -INFINITY;
      for (int nt = 0; nt < 4; ++nt) {
        float sv = s[nt][r] * scale;
        if (diag && (nt * 16 + l16 > qrow_l)) sv = -INFINITY;
        s[nt][r] = sv;
        mt = fmaxf(mt, sv);
      }
      for (int m = 1; m < 16; m <<= 1) mt = fmaxf(mt, __shfl_xor(mt, m, 16));
      const float mn = fmaxf(mrun[r], mt);
      alpha[r] = expf(mrun[r] - mn);
      float rs = 0.f;
      for (int nt = 0; nt < 4; ++nt) {
        float pv = expf(s[nt][r] - mn);
        p[nt][r] = pv;
        rs += pv;
      }
      for (int m = 1; m < 16; m <<= 1) rs += __shfl_xor(rs, m, 16);
      lrun[r] = lrun[r] * alpha[r] + rs;
      mrun[r] = mn;
    }
    for (int nt = 0; nt < 4; ++nt)
      for (int r = 0; r < 4; ++r) o[nt][r] *= alpha[r];
    // P: C-layout -> LDS -> A-layout
    short* pw = pl + wave * 16 * 72;
    for (int nt = 0; nt < 4; ++nt)
      for (int r = 0; r < 4; ++r)
        pw[(quad * 4 + r) * 72 + nt * 16 + l16] = f2bf(p[nt][r]);
    __syncthreads();
    short8v af0 = *(const short8v*)&pw[l16 * 72 + quad * 8];
    short8v af1 = *(const short8v*)&pw[l16 * 72 + 32 + quad * 8];
    for (int nt = 0; nt < 4; ++nt) {
      short8v b0 = *(const short8v*)&vt[(nt * 16 + l16) * 72 + quad * 8];
      short8v b1 = *(const short8v*)&vt[(nt * 16 + l16) * 72 + 32 + quad * 8];
      o[nt] = __builtin_amdgcn_mfma_f32_16x16x32_bf16(af0, b0, o[nt], 0, 0, 0);
      o[nt] = __builtin_amdgcn_mfma_f32_16x16x32_bf16(af1, b1, o[nt], 0, 0, 0);
    }
  }
  for (int nt = 0; nt < 4; ++nt)
    for (int r = 0; r < 4; ++r) {
      int row = bb * SEQ + qt * 64 + wave * 16 + quad * 4 + r;
      y[(size_t)row * EMB + h * 64 + nt * 16 + l16] = f2bf(o[nt][r] / lrun[r]);
    }
}

// ---------------- cross-entropy (single-pass online logsumexp) --------------
__global__ __launch_bounds__(256) void nll_kernel(const float* __restrict__ logits,
    const int* __restrict__ tgt, float* __restrict__ nll) {
  const int row = blockIdx.x, tid = threadIdx.x;
  const int wave = tid >> 6, lane = tid & 63;
  const float* lr = logits + (size_t)row * NVOCAB;
  __shared__ float rm[4], rs[4];
  float m = -INFINITY, s = 0.f;
  for (int j = tid; j < NVOCAB; j += 256) {
    float v = lr[j];
    if (v <= m) {
      s += expf(v - m);
    } else {
      s = s * expf(m - v) + 1.f;
      m = v;
    }
  }
  for (int t = 1; t < 64; t <<= 1) {
    float m2 = __shfl_xor(m, t, 64);
    float s2 = __shfl_xor(s, t, 64);
    float mn = fmaxf(m, m2);
    s = s * expf(m - mn) + s2 * expf(m2 - mn);
    m = mn;
  }
  if (lane == 0) { rm[wave] = m; rs[wave] = s; }
  __syncthreads();
  if (tid == 0) {
    m = rm[0]; s = rs[0];
    for (int w = 1; w < 4; ++w) {
      float mn = fmaxf(m, rm[w]);
      s = s * expf(m - mn) + rs[w] * expf(rm[w] - mn);
      m = mn;
    }
    int t = tgt[row];
    nll[row] = (t >= 0) ? (m + logf(s) - lr[t]) : 0.f;
  }
}

__global__ __launch_bounds__(256) void loss_kernel(const float* __restrict__ nll,
    const int* __restrict__ tgt, float* __restrict__ out) {
  const int tid = threadIdx.x, wave = tid >> 6, lane = tid & 63;
  __shared__ float rs[4], rc[4];
  float s = 0.f, c = 0.f;
  for (int i = tid; i < NROWS; i += 256) {
    s += nll[i];
    c += (tgt[i] >= 0) ? 1.f : 0.f;
  }
  for (int t = 1; t < 64; t <<= 1) { s += __shfl_xor(s, t, 64); c += __shfl_xor(c, t, 64); }
  if (lane == 0) { rs[wave] = s; rc[wave] = c; }
  __syncthreads();
  if (tid == 0) {
    s = rs[0] + rs[1] + rs[2] + rs[3];
    c = rc[0] + rc[1] + rc[2] + rc[3];
    out[0] = s / fmaxf(c, 1.f);
  }
}

// ---------------- host ----------------
extern "C" void kernel_launch(void* const* d_in, const int* in_sizes, int n_in,
                              void* d_out, int out_size, void* d_ws, size_t ws_size,
                              hipStream_t stream) {
  const int*   idx    = (const int*)d_in[0];
  const int*   tgt    = (const int*)d_in[1];
  const float* wte    = (const float*)d_in[2];
  const float* wpe    = (const float*)d_in[3];
  const float* ln1w   = (const float*)d_in[4];
  const float* ln1b   = (const float*)d_in[5];
  const float* attnw  = (const float*)d_in[6];
  const float* attnpw = (const float*)d_in[7];
  const float* ln2w   = (const float*)d_in[8];
  const float* ln2b   = (const float*)d_in[9];
  const float* fcw    = (const float*)d_in[10];
  const float* fcpw   = (const float*)d_in[11];
  const float* lnfw   = (const float*)d_in[12];
  const float* lnfb   = (const float*)d_in[13];
  const float* lmw    = (const float*)d_in[14];
  float* out = (float*)d_out;

  // workspace layout (~204 MB)
  float* x    = (float*)d_ws;                               // 4096*1024 f32
  short* hbuf = (short*)(x + (size_t)NROWS * EMB);          // 4096*1024 bf16
  short* qkvb = hbuf + (size_t)NROWS * EMB;                 // 4096*3072 bf16
  short* yb   = qkvb + (size_t)NROWS * QKVD;                // 4096*1024 bf16
  short* fcb  = yb   + (size_t)NROWS * EMB;                 // 4096*4096 bf16
  short* wsc  = fcb  + (size_t)NROWS * FFDIM;               // 4096*1024 bf16 scratch
  short* lmwb = wsc  + (size_t)FFDIM * EMB;                 // 50304*1024 bf16
  float* nll  = (float*)(lmwb + (size_t)NVOC_PAD * EMB);    // 4096 f32

  auto conv = [&](const float* src, short* dst, long long n) {
    int grid = (int)((n / 8 + 255) / 256);
    if (grid > 2048) grid = 2048;
    convbf_kernel<<<grid, 256, 0, stream>>>(src, dst, n, n);
  };

  embed_kernel<<<NROWS, 256, 0, stream>>>(idx, wte, wpe, x);
  // lm_head weights -> bf16 once, zero-padded to 50304 rows
  convbf_kernel<<<2048, 256, 0, stream>>>(lmw, lmwb,
      (long long)NVOC_PAD * EMB, (long long)NVOCAB * EMB);

  for (int i = 0; i < NLAY; ++i) {
    ln_kernel<<<NROWS, 256, 0, stream>>>(x, ln1w + i * EMB, ln1b + i * EMB, hbuf);
    conv(attnw + (size_t)i * QKVD * EMB, wsc, (long long)QKVD * EMB);
    gemm_bt<<<dim3(QKVD / 128, NROWS / 128), 256, 0, stream>>>(
        hbuf, wsc, (float*)qkvb, nullptr, NROWS, QKVD, EMB, 2);
    attn_kernel<<<dim3(SEQ / 64, NHEAD, NBATCH), 256, 0, stream>>>(qkvb, yb);
    conv(attnpw + (size_t)i * EMB * EMB, wsc, (long long)EMB * EMB);
    gemm_bt<<<dim3(EMB / 128, NROWS / 128), 256, 0, stream>>>(
        yb, wsc, x, x, NROWS, EMB, EMB, 1);
    ln_kernel<<<NROWS, 256, 0, stream>>>(x, ln2w + i * EMB, ln2b + i * EMB, hbuf);
    conv(fcw + (size_t)i * FFDIM * EMB, wsc, (long long)FFDIM * EMB);
    gemm_bt<<<dim3(FFDIM / 128, NROWS / 128), 256, 0, stream>>>(
        hbuf, wsc, (float*)fcb, nullptr, NROWS, FFDIM, EMB, 3);
    conv(fcpw + (size_t)i * EMB * FFDIM, wsc, (long long)EMB * FFDIM);
    gemm_bt<<<dim3(EMB / 128, NROWS / 128), 256, 0, stream>>>(
        fcb, wsc, x, x, NROWS, EMB, FFDIM, 1);
  }
  ln_kernel<<<NROWS, 256, 0, stream>>>(x, lnfw, lnfb, hbuf);
  gemm_bt<<<dim3(NVOC_PAD / 128, NROWS / 128), 256, 0, stream>>>(
      hbuf, lmwb, out, nullptr, NROWS, NVOCAB, EMB, 0);
  nll_kernel<<<NROWS, 256, 0, stream>>>(out, tgt, nll);
  loss_kernel<<<1, 256, 0, stream>>>(nll, tgt, out + (size_t)NROWS * NVOCAB);
}